// Round 7
// baseline (209.327 us; speedup 1.0000x reference)
//
#include <hip/hip_runtime.h>

typedef unsigned short u16;
typedef unsigned int   u32;
typedef float  f32x16 __attribute__((ext_vector_type(16)));
typedef __bf16 bf16x8 __attribute__((ext_vector_type(8)));
typedef u16    u16x8  __attribute__((ext_vector_type(8)));

#define NB     1024      // batch rows (M)
#define NN     8193      // output cols; true K = 8193
#define K2R    8256      // K padded to 129*64
#define NT     129       // K tiles of BK=64
#define ABF_LEN 16704    // a padded (true length 16385)
#define NFRAG  1040      // 32-wide Hankel fragment blocks (1KB each)

// workspace byte offsets (256-aligned)
#define OFF_BANDS 0u
#define OFF_ABF   74496u      // 16704*2 = 33408
#define OFF_BFRAG 108032u     // 1040*1024 = 1064960
#define OFF_UREV  1175040u    // 1024*8256*2

__device__ __forceinline__ u16 f2bf(float f) {
  u32 u = __builtin_bit_cast(u32, f);
  return (u16)((u + 0x7FFFu + ((u >> 16) & 1u)) >> 16);
}
__device__ __forceinline__ float bf2f(u16 h) {
  u32 u = ((u32)h) << 16;
  return __builtin_bit_cast(float, u);
}

// ---------------- kernel a construction ----------------
__global__ void k_bands(const float* __restrict__ x,
                        const float* __restrict__ W1, const float* __restrict__ b1,
                        const float* __restrict__ W2, const float* __restrict__ b2,
                        const float* __restrict__ W3, const float* __restrict__ b3,
                        float* __restrict__ bands) {
  const int j = blockIdx.y;
  __shared__ float w2s[4096];
  __shared__ float w1s[64], b1s[64], b2s[64], w3s[64];
  for (int i = threadIdx.x; i < 4096; i += 256) w2s[i] = W2[j * 4096 + i];
  if (threadIdx.x < 64) {
    w1s[threadIdx.x] = W1[j * 64 + threadIdx.x];
    b1s[threadIdx.x] = b1[j * 64 + threadIdx.x];
    b2s[threadIdx.x] = b2[j * 64 + threadIdx.x];
    w3s[threadIdx.x] = W3[j * 64 + threadIdx.x];
  }
  __syncthreads();
  const int k = blockIdx.x * 256 + threadIdx.x;
  if (k >= 2049) return;
  const float xc = x[8 * k];
  float h1[64];
  #pragma unroll
  for (int o = 0; o < 64; ++o) h1[o] = tanhf(w1s[o] * xc + b1s[o]);
  float outv = b3[j];
  for (int o = 0; o < 64; ++o) {
    float a0 = 0.f, a1 = 0.f, a2 = 0.f, a3 = 0.f;
    #pragma unroll
    for (int c = 0; c < 64; c += 4) {
      a0 += w2s[o * 64 + c] * h1[c];
      a1 += w2s[o * 64 + c + 1] * h1[c + 1];
      a2 += w2s[o * 64 + c + 2] * h1[c + 2];
      a3 += w2s[o * 64 + c + 3] * h1[c + 3];
    }
    outv += w3s[o] * tanhf(b2s[o] + ((a0 + a1) + (a2 + a3)));
  }
  bands[j * 2049 + k] = outv;
}

// fused interp: lvl1 (LDS) -> lvl2 (LDS) -> lvl3 (abf, bf16). One block.
__global__ void k_interp(const float* __restrict__ bands, u16* __restrict__ abf) {
  __shared__ float s1[4097];
  __shared__ float s2[8193];
  const int tid = threadIdx.x;
  const float* bd0 = bands;
  const float* bd1 = bands + 2049;
  const float* bd2 = bands + 2 * 2049;
  for (int i = tid; i < 4097; i += 1024) {
    float v = (i & 1) ? 0.5f * (bd0[i >> 1] + bd0[(i >> 1) + 1]) : bd0[i >> 1];
    if (i >= 512 && i < 2561) v = bd1[i - 512];
    s1[i] = v;
  }
  __syncthreads();
  for (int i = tid; i < 8193; i += 1024) {
    float v = (i & 1) ? 0.5f * (s1[i >> 1] + s1[(i >> 1) + 1]) : s1[i >> 1];
    if (i >= 1024 && i < 3073) v = bd2[i - 1024];
    s2[i] = v;
  }
  __syncthreads();
  for (int i = tid; i < ABF_LEN; i += 1024) {
    float v = 0.f;
    if (i <= 16384)
      v = (i & 1) ? 0.5f * (s2[i >> 1] + s2[(i >> 1) + 1]) : s2[i >> 1];
    abf[i] = f2bf(v);
  }
}

// urev[b][j] = bf16(u[b][8192-j]) for j<=8192 else 0 (row stride K2R)
__global__ void k_urev(const float* __restrict__ u, u16* __restrict__ urev) {
  const int b = blockIdx.y;
  const int c = blockIdx.x * 256 + threadIdx.x;
  if (c >= K2R / 8) return;
  const int j0 = c * 8;
  const float* ub = u + (size_t)b * NN;
  u16x8 v;
  #pragma unroll
  for (int r = 0; r < 8; ++r) {
    const int jr = j0 + r;
    const float f = (jr <= 8192) ? ub[8192 - jr] : 0.f;
    v[r] = f2bf(f);
  }
  *(u16x8*)&urev[(size_t)b * K2R + j0] = v;
}

// 32-wide Hankel fragments (R3-validated) for mfma_32x32x16 B-operand:
// Bfrag[f][lane][idx] = abf[16f + (lane&31) + 8*(lane>>5) + idx]
__global__ void k_bfrag(const u16* __restrict__ abf, u16* __restrict__ bfr) {
  const int g = blockIdx.x * 256 + threadIdx.x;
  if (g >= NFRAG * 64) return;
  const int t = g >> 6, l = g & 63;
  const int s = 16 * t + (l & 31) + ((l >> 5) << 3);
  u16x8 v;
  #pragma unroll
  for (int r = 0; r < 8; ++r) v[r] = abf[s + r];
  *(u16x8*)&bfr[(size_t)g * 8] = v;
}

// column 8192: w[b,8192] = sum_j urev[b,j] * abf[8192+j]
__global__ void k_lastcol(const u16* __restrict__ urev, const u16* __restrict__ abf,
                          float* __restrict__ out) {
  const int b = blockIdx.x;
  const int tid = threadIdx.x;
  float s = 0.f;
  #pragma unroll
  for (int it = 0; it < 5; ++it) {
    const int c = tid + 256 * it;
    if (c < K2R / 8) {
      u16x8 uv = *(const u16x8*)&urev[(size_t)b * K2R + c * 8];
      u16x8 av = *(const u16x8*)&abf[8192 + c * 8];
      #pragma unroll
      for (int r = 0; r < 8; ++r) s += bf2f(uv[r]) * bf2f(av[r]);
    }
  }
  #pragma unroll
  for (int off = 32; off >= 1; off >>= 1) s += __shfl_xor(s, off, 64);
  __shared__ float red[4];
  if ((tid & 63) == 0) red[tid >> 6] = s;
  __syncthreads();
  if (tid == 0) out[(size_t)b * NN + 8192] = red[0] + red[1] + red[2] + red[3];
}

// ---------------- main Hankel GEMM ----------------
// BM=128 x BN=128 x BK=64, 256 threads (4 waves 2Mx2N), 32x32x16 MFMA
// (per-wave 64x64 as 2x2 32-blocks x 4 k-steps). A in LDS (both-sides XOR
// swizzle, double-buffered, 32KB total); B fragments loaded DIRECTLY from the
// L2-resident table into registers (6 frags/wave/tile, double-banked bX/bY;
// the compiler tracks these reg deps with its own exact vmcnt). R6's
// tripwire-clean 4-phase skeleton: per phase {4 ds_read, issue loads,
// s_barrier, lgkmcnt(0), setprio(1), 8 MFMA, setprio(0)}, tile-end
// vmcnt(6) (A-stage retired, 6 B loads stay in flight) + s_barrier.
// Grid 512 = 2 blocks/CU.
__device__ __forceinline__ void gload16(const void* g, void* l) {
  __builtin_amdgcn_global_load_lds((__attribute__((address_space(1))) void*)(void*)g,
                                   (__attribute__((address_space(3))) void*)l, 16, 0, 0);
}

__global__ __launch_bounds__(256, 2) void k_gemm(const u16* __restrict__ urev,
                                                 const u16* __restrict__ bfrag,
                                                 float* __restrict__ out) {
  __shared__ u16 Ab[2][8192];   // [128 rows][8 slots of 8 bf16], 16KB each
  const int tid  = threadIdx.x;
  const int lane = tid & 63;
  const int wid  = tid >> 6;
  const int wr   = wid >> 1;   // 0..1  (64-row slice)
  const int wc   = wid & 1;    // 0..1  (64-col slice)

  // 512 blocks: by = XCD id (round-robin), 64 bx share one 2.1MB A-panel per XCD
  const int by = blockIdx.x & 7;
  const int bx = blockIdx.x >> 3;
  const int b0 = by * 128;
  const int i0 = bx * 128;
  const int F0 = bx * 8;       // base fragment at t=0

  // A staging: 1024 x 16B chunks, 4/thread; chunk=(row,slot), src slot = slot^(row&7)
  const u16* aSrc[4];
  #pragma unroll
  for (int r = 0; r < 4; ++r) {
    const int ch = tid + (r << 8);
    aSrc[r] = urev + (size_t)(b0 + (ch >> 3)) * K2R + (((ch & 7) ^ ((ch >> 3) & 7)) << 3);
  }
  // per-wave B fragment pointer: frag(t, n, kt) = F0 + 4t + 4wc + 2n + kt
  const u16* bW = bfrag + (((size_t)(F0 + (wc << 2))) << 9) + (lane << 3);

  f32x16 acc[2][2] = {};
  bf16x8 af[4];
  bf16x8 bX[6], bY[6];

  auto stageA = [&](int buf, int t) {
    const int j0 = t << 6;
    #pragma unroll
    for (int r = 0; r < 4; ++r)
      gload16(aSrc[r] + j0, &Ab[buf][(tid + (r << 8)) << 3]);
  };
  auto loadB = [&](bf16x8* bk, int t) {
    const u16* p = bW + ((size_t)t << 11);   // +4t fragments
    #pragma unroll
    for (int j = 0; j < 6; ++j)
      bk[j] = *reinterpret_cast<const bf16x8*>(p + (j << 9));
  };
  auto dsA = [&](int buf, int p) {           // phase p: k-steps 2p, 2p+1
    #pragma unroll
    for (int ktl = 0; ktl < 2; ++ktl)
      #pragma unroll
      for (int m = 0; m < 2; ++m) {
        const int row  = (wr << 6) + (m << 5) + (lane & 31);
        const int kt   = (p << 1) + ktl;
        const int slot = ((lane >> 5) + (kt << 1)) ^ (row & 7);
        af[(ktl << 1) + m] = *reinterpret_cast<const bf16x8*>(&Ab[buf][(row << 6) + (slot << 3)]);
      }
  };
  auto mm8 = [&](const bf16x8* bk, int p) {
    #pragma unroll
    for (int ktl = 0; ktl < 2; ++ktl)
      #pragma unroll
      for (int m = 0; m < 2; ++m)
        #pragma unroll
        for (int n = 0; n < 2; ++n)
          acc[m][n] = __builtin_amdgcn_mfma_f32_32x32x16_bf16(
              af[(ktl << 1) + m], bk[(n << 1) + (p << 1) + ktl], acc[m][n], 0, 0, 0);
  };

#define PHASE(dbuf, pp, bank, ISSUE, TAIL)                        \
  {                                                               \
    dsA(dbuf, pp);                                                \
    __builtin_amdgcn_sched_barrier(0);                            \
    ISSUE;                                                        \
    __builtin_amdgcn_sched_barrier(0);                            \
    __builtin_amdgcn_s_barrier();                                 \
    asm volatile("s_waitcnt lgkmcnt(0)" ::: "memory");            \
    __builtin_amdgcn_sched_barrier(0);                            \
    __builtin_amdgcn_s_setprio(1);                                \
    mm8(bank, pp);                                                \
    __builtin_amdgcn_s_setprio(0);                                \
    __builtin_amdgcn_sched_barrier(0);                            \
    TAIL;                                                         \
    __builtin_amdgcn_s_barrier();                                 \
  }

  // ---- prologue: A(0)->buf0, B(0)->bX
  stageA(0, 0);
  __builtin_amdgcn_sched_barrier(0);
  loadB(bX, 0);
  __builtin_amdgcn_sched_barrier(0);
  asm volatile("s_waitcnt vmcnt(6)" ::: "memory");
  __builtin_amdgcn_s_barrier();

  // ---- main loop: tile pairs (even: buf0/bX, odd: buf1/bY)
  #pragma unroll 1
  for (int t = 0; t < NT - 1; t += 2) {
    PHASE(0, 0, bX, stageA(1, t + 1), );
    PHASE(0, 1, bX, loadB(bY, t + 1),
          asm volatile("s_waitcnt vmcnt(6)" ::: "memory"));
    PHASE(1, 0, bY, stageA(0, t + 2), );
    PHASE(1, 1, bY, loadB(bX, t + 2),
          asm volatile("s_waitcnt vmcnt(6)" ::: "memory"));
  }
#undef PHASE

  // ---- epilogue: tile 128 (even, buf0, bX), no staging/barriers
  dsA(0, 0);
  asm volatile("s_waitcnt lgkmcnt(0)" ::: "memory");
  __builtin_amdgcn_sched_barrier(0);
  mm8(bX, 0);
  dsA(0, 1);
  asm volatile("s_waitcnt lgkmcnt(0)" ::: "memory");
  __builtin_amdgcn_sched_barrier(0);
  mm8(bX, 1);

  // C-write (R3-validated 32x32 layout): col = lane&31, row = (r&3)+8*(r>>2)+4*(lane>>5)
  const int cb = i0 + (wc << 6) + (lane & 31);
  const int rb = b0 + (wr << 6) + ((lane >> 5) << 2);
  #pragma unroll
  for (int m = 0; m < 2; ++m)
    #pragma unroll
    for (int n = 0; n < 2; ++n) {
      #pragma unroll
      for (int r = 0; r < 16; ++r) {
        const int row = rb + (m << 5) + (r & 3) + ((r >> 2) << 3);
        const int col = cb + (n << 5);
        out[(size_t)row * NN + col] = acc[m][n][r];
      }
    }
}

extern "C" void kernel_launch(void* const* d_in, const int* in_sizes, int n_in,
                              void* d_out, int out_size, void* d_ws, size_t ws_size,
                              hipStream_t stream) {
  (void)in_sizes; (void)n_in; (void)out_size; (void)ws_size;
  const float* u  = (const float*)d_in[0];
  const float* x  = (const float*)d_in[1];
  const float* W1 = (const float*)d_in[2];
  const float* b1 = (const float*)d_in[3];
  const float* W2 = (const float*)d_in[4];
  const float* b2 = (const float*)d_in[5];
  const float* W3 = (const float*)d_in[6];
  const float* b3 = (const float*)d_in[7];
  float* out = (float*)d_out;
  char*  ws  = (char*)d_ws;

  float* bands = (float*)(ws + OFF_BANDS);
  u16*   abf   = (u16*)(ws + OFF_ABF);
  u16*   bfr   = (u16*)(ws + OFF_BFRAG);
  u16*   urev  = (u16*)(ws + OFF_UREV);

  k_bands<<<dim3(9, 3), 256, 0, stream>>>(x, W1, b1, W2, b2, W3, b3, bands);
  k_interp<<<1, 1024, 0, stream>>>(bands, abf);
  k_urev<<<dim3(5, 1024), 256, 0, stream>>>(u, urev);
  k_bfrag<<<260, 256, 0, stream>>>(abf, bfr);
  k_lastcol<<<1024, 256, 0, stream>>>(urev, abf, out);
  k_gemm<<<512, 256, 0, stream>>>(urev, bfr, out);
}

// Round 8
// 194.372 us; speedup vs baseline: 1.0769x; 1.0769x over previous
//
#include <hip/hip_runtime.h>

typedef unsigned short u16;
typedef unsigned int   u32;
typedef float  f32x4  __attribute__((ext_vector_type(4)));
typedef __bf16 bf16x8 __attribute__((ext_vector_type(8)));
typedef u16    u16x8  __attribute__((ext_vector_type(8)));

#define NB     1024      // batch rows (M)
#define NN     8193      // output cols; true K = 8193
#define K2R    8256      // K padded to 129*64
#define NT     129       // K tiles of BK=64
#define ABF_LEN 16704    // a padded (true length 16385)
#define NFRAG  1032      // 16-wide Hankel fragment blocks (1KB each)

// workspace byte offsets (256-aligned)
#define OFF_BANDS 0u
#define OFF_ABF   74496u      // 16704*2 = 33408
#define OFF_BFRAG 108032u     // 1032*1024
#define OFF_UREV  1175040u    // 1024*8256*2

__device__ __forceinline__ u16 f2bf(float f) {
  u32 u = __builtin_bit_cast(u32, f);
  return (u16)((u + 0x7FFFu + ((u >> 16) & 1u)) >> 16);
}
__device__ __forceinline__ float bf2f(u16 h) {
  u32 u = ((u32)h) << 16;
  return __builtin_bit_cast(float, u);
}

// ---------------- kernel a construction ----------------
__global__ void k_bands(const float* __restrict__ x,
                        const float* __restrict__ W1, const float* __restrict__ b1,
                        const float* __restrict__ W2, const float* __restrict__ b2,
                        const float* __restrict__ W3, const float* __restrict__ b3,
                        float* __restrict__ bands) {
  const int j = blockIdx.y;
  __shared__ float w2s[4096];
  __shared__ float w1s[64], b1s[64], b2s[64], w3s[64];
  for (int i = threadIdx.x; i < 4096; i += 256) w2s[i] = W2[j * 4096 + i];
  if (threadIdx.x < 64) {
    w1s[threadIdx.x] = W1[j * 64 + threadIdx.x];
    b1s[threadIdx.x] = b1[j * 64 + threadIdx.x];
    b2s[threadIdx.x] = b2[j * 64 + threadIdx.x];
    w3s[threadIdx.x] = W3[j * 64 + threadIdx.x];
  }
  __syncthreads();
  const int k = blockIdx.x * 256 + threadIdx.x;
  if (k >= 2049) return;
  const float xc = x[8 * k];
  float h1[64];
  #pragma unroll
  for (int o = 0; o < 64; ++o) h1[o] = tanhf(w1s[o] * xc + b1s[o]);
  float outv = b3[j];
  for (int o = 0; o < 64; ++o) {
    float a0 = 0.f, a1 = 0.f, a2 = 0.f, a3 = 0.f;
    #pragma unroll
    for (int c = 0; c < 64; c += 4) {
      a0 += w2s[o * 64 + c] * h1[c];
      a1 += w2s[o * 64 + c + 1] * h1[c + 1];
      a2 += w2s[o * 64 + c + 2] * h1[c + 2];
      a3 += w2s[o * 64 + c + 3] * h1[c + 3];
    }
    outv += w3s[o] * tanhf(b2s[o] + ((a0 + a1) + (a2 + a3)));
  }
  bands[j * 2049 + k] = outv;
}

// fused interp: lvl1 (LDS) -> lvl2 (LDS) -> lvl3 (abf, bf16). One block.
__global__ void k_interp(const float* __restrict__ bands, u16* __restrict__ abf) {
  __shared__ float s1[4097];
  __shared__ float s2[8193];
  const int tid = threadIdx.x;
  const float* bd0 = bands;
  const float* bd1 = bands + 2049;
  const float* bd2 = bands + 2 * 2049;
  for (int i = tid; i < 4097; i += 1024) {
    float v = (i & 1) ? 0.5f * (bd0[i >> 1] + bd0[(i >> 1) + 1]) : bd0[i >> 1];
    if (i >= 512 && i < 2561) v = bd1[i - 512];
    s1[i] = v;
  }
  __syncthreads();
  for (int i = tid; i < 8193; i += 1024) {
    float v = (i & 1) ? 0.5f * (s1[i >> 1] + s1[(i >> 1) + 1]) : s1[i >> 1];
    if (i >= 1024 && i < 3073) v = bd2[i - 1024];
    s2[i] = v;
  }
  __syncthreads();
  for (int i = tid; i < ABF_LEN; i += 1024) {
    float v = 0.f;
    if (i <= 16384)
      v = (i & 1) ? 0.5f * (s2[i >> 1] + s2[(i >> 1) + 1]) : s2[i >> 1];
    abf[i] = f2bf(v);
  }
}

// urev[b][j] = bf16(u[b][8192-j]) for j<=8192 else 0 (row stride K2R)
__global__ void k_urev(const float* __restrict__ u, u16* __restrict__ urev) {
  const int b = blockIdx.y;
  const int c = blockIdx.x * 256 + threadIdx.x;
  if (c >= K2R / 8) return;
  const int j0 = c * 8;
  const float* ub = u + (size_t)b * NN;
  u16x8 v;
  #pragma unroll
  for (int r = 0; r < 8; ++r) {
    const int jr = j0 + r;
    const float f = (jr <= 8192) ? ub[8192 - jr] : 0.f;
    v[r] = f2bf(f);
  }
  *(u16x8*)&urev[(size_t)b * K2R + j0] = v;
}

// 16-wide Hankel fragments (R1/R6-proven) for mfma_16x16x32 B-operand:
// Bfrag[f][lane][idx] = abf[16f + (lane&15) + 8*(lane>>4) + idx]
__global__ void k_bfrag(const u16* __restrict__ abf, u16* __restrict__ bfr) {
  const int g = blockIdx.x * 256 + threadIdx.x;
  if (g >= NFRAG * 64) return;
  const int t = g >> 6, l = g & 63;
  const int s = 16 * t + (l & 15) + ((l >> 4) << 3);
  u16x8 v;
  #pragma unroll
  for (int r = 0; r < 8; ++r) v[r] = abf[s + r];
  *(u16x8*)&bfr[(size_t)g * 8] = v;
}

// column 8192: w[b,8192] = sum_j urev[b,j] * abf[8192+j]
__global__ void k_lastcol(const u16* __restrict__ urev, const u16* __restrict__ abf,
                          float* __restrict__ out) {
  const int b = blockIdx.x;
  const int tid = threadIdx.x;
  float s = 0.f;
  #pragma unroll
  for (int it = 0; it < 5; ++it) {
    const int c = tid + 256 * it;
    if (c < K2R / 8) {
      u16x8 uv = *(const u16x8*)&urev[(size_t)b * K2R + c * 8];
      u16x8 av = *(const u16x8*)&abf[8192 + c * 8];
      #pragma unroll
      for (int r = 0; r < 8; ++r) s += bf2f(uv[r]) * bf2f(av[r]);
    }
  }
  #pragma unroll
  for (int off = 32; off >= 1; off >>= 1) s += __shfl_xor(s, off, 64);
  __shared__ float red[4];
  if ((tid & 63) == 0) red[tid >> 6] = s;
  __syncthreads();
  if (tid == 0) out[(size_t)b * NN + 8192] = red[0] + red[1] + red[2] + red[3];
}

// ---------------- main Hankel GEMM ----------------
// BM=128 x BN=128 x BK=64, 256 threads (4 waves 2Mx2N), 16x16x32 MFMA.
// A in LDS: R6's proven conflict-free path (both-sides XOR swizzle, dbuf,
// 32KB total). B: R7's proven reg-direct path (6 coalesced 1KB frag loads
// per wave per tile from the L2-resident table, double-banked bX/bY; the
// compiler inserts exact vmcnt waits for the reg deps). R6's tripwire-clean
// 4-phase skeleton: per phase {4 ds_read, issue loads, s_barrier, lgkmcnt(0),
// setprio(1), 16 MFMA, setprio(0)}, tile-end vmcnt(6) (retires exactly the
// 4 A-gloads, 6 B loads stay in flight) + s_barrier. Grid 512 = 2 blocks/CU.
__device__ __forceinline__ void gload16(const void* g, void* l) {
  __builtin_amdgcn_global_load_lds((__attribute__((address_space(1))) void*)(void*)g,
                                   (__attribute__((address_space(3))) void*)l, 16, 0, 0);
}

__global__ __launch_bounds__(256, 2) void k_gemm(const u16* __restrict__ urev,
                                                 const u16* __restrict__ bfrag,
                                                 float* __restrict__ out) {
  __shared__ u16 Ab[2][8192];   // [128 rows][8 slots of 8 bf16], 16KB each
  const int tid  = threadIdx.x;
  const int lane = tid & 63;
  const int wid  = tid >> 6;
  const int wr   = wid >> 1;   // 0..1  (64-row slice)
  const int wc   = wid & 1;    // 0..1  (64-col slice)

  // 512 blocks: by = XCD id (round-robin), 64 bx share one 2.1MB A-panel per XCD
  const int by = blockIdx.x & 7;
  const int bx = blockIdx.x >> 3;
  const int b0 = by * 128;
  const int i0 = bx * 128;
  const int F0 = bx * 8;       // base fragment at t=0

  // A staging: 1024 x 16B chunks, 4/thread; chunk=(row,slot), src slot = slot^(row&7)
  const u16* aSrc[4];
  #pragma unroll
  for (int r = 0; r < 4; ++r) {
    const int ch = tid + (r << 8);
    aSrc[r] = urev + (size_t)(b0 + (ch >> 3)) * K2R + (((ch & 7) ^ ((ch >> 3) & 7)) << 3);
  }
  // per-wave B fragment pointer: frag(t, n, kk) = F0 + 4t + 4wc + n + 2kk
  const u16* bW = bfrag + (((size_t)(F0 + (wc << 2))) << 9) + (lane << 3);

  f32x4 acc[4][4] = {};
  bf16x8 af[4];
  bf16x8 bX[6], bY[6];

  auto stageA = [&](int buf, int t) {
    const int j0 = t << 6;
    #pragma unroll
    for (int r = 0; r < 4; ++r)
      gload16(aSrc[r] + j0, &Ab[buf][(tid + (r << 8)) << 3]);
  };
  auto loadB = [&](bf16x8* bk, int t) {
    const u16* p = bW + ((size_t)t << 11);   // +4t fragments
    #pragma unroll
    for (int j = 0; j < 6; ++j)
      bk[j] = *reinterpret_cast<const bf16x8*>(p + (j << 9));
  };
  auto dsA = [&](int buf, int kk) {
    #pragma unroll
    for (int m = 0; m < 4; ++m) {
      const int row  = (wr << 6) + (m << 4) + (lane & 15);
      const int slot = ((lane >> 4) + (kk << 2)) ^ (row & 7);
      af[m] = *reinterpret_cast<const bf16x8*>(&Ab[buf][(row << 6) + (slot << 3)]);
    }
  };
  auto mm16 = [&](const bf16x8* bk, int kk) {
    #pragma unroll
    for (int m = 0; m < 4; ++m)
      #pragma unroll
      for (int n = 0; n < 4; ++n)
        acc[m][n] = __builtin_amdgcn_mfma_f32_16x16x32_bf16(
            af[m], bk[n + (kk << 1)], acc[m][n], 0, 0, 0);
  };

#define PHASE(dbuf, kk, bank, ISSUE, TAIL)                        \
  {                                                               \
    dsA(dbuf, kk);                                                \
    __builtin_amdgcn_sched_barrier(0);                            \
    ISSUE;                                                        \
    __builtin_amdgcn_sched_barrier(0);                            \
    __builtin_amdgcn_s_barrier();                                 \
    asm volatile("s_waitcnt lgkmcnt(0)" ::: "memory");            \
    __builtin_amdgcn_sched_barrier(0);                            \
    __builtin_amdgcn_s_setprio(1);                                \
    mm16(bank, kk);                                               \
    __builtin_amdgcn_s_setprio(0);                                \
    __builtin_amdgcn_sched_barrier(0);                            \
    TAIL;                                                         \
    __builtin_amdgcn_s_barrier();                                 \
  }

  // ---- prologue: A(0)->buf0, B(0)->bX
  stageA(0, 0);
  __builtin_amdgcn_sched_barrier(0);
  loadB(bX, 0);
  __builtin_amdgcn_sched_barrier(0);
  asm volatile("s_waitcnt vmcnt(6)" ::: "memory");
  __builtin_amdgcn_s_barrier();

  // ---- main loop: tile pairs (even: buf0/bX, odd: buf1/bY)
  #pragma unroll 1
  for (int t = 0; t < NT - 1; t += 2) {
    PHASE(0, 0, bX, stageA(1, t + 1), );
    PHASE(0, 1, bX, loadB(bY, t + 1),
          asm volatile("s_waitcnt vmcnt(6)" ::: "memory"));
    PHASE(1, 0, bY, stageA(0, t + 2), );
    PHASE(1, 1, bY, loadB(bX, t + 2),
          asm volatile("s_waitcnt vmcnt(6)" ::: "memory"));
  }
#undef PHASE

  // ---- epilogue: tile 128 (even, buf0, bX), no staging/barriers
  dsA(0, 0);
  asm volatile("s_waitcnt lgkmcnt(0)" ::: "memory");
  __builtin_amdgcn_sched_barrier(0);
  mm16(bX, 0);
  dsA(0, 1);
  asm volatile("s_waitcnt lgkmcnt(0)" ::: "memory");
  __builtin_amdgcn_sched_barrier(0);
  mm16(bX, 1);

  // C-write (R1/R6-proven 16x16 layout): col = lane&15 (+16n), row = 4*(lane>>4)+r
  #pragma unroll
  for (int n = 0; n < 4; ++n) {
    const int col = i0 + (wc << 6) + (n << 4) + (lane & 15);  // max 8191 < NN
    #pragma unroll
    for (int m = 0; m < 4; ++m) {
      const int rowb = b0 + (wr << 6) + (m << 4) + ((lane >> 4) << 2);
      float* o = out + (size_t)rowb * NN + col;
      #pragma unroll
      for (int r = 0; r < 4; ++r) o[(size_t)r * NN] = acc[m][n][r];
    }
  }
}

extern "C" void kernel_launch(void* const* d_in, const int* in_sizes, int n_in,
                              void* d_out, int out_size, void* d_ws, size_t ws_size,
                              hipStream_t stream) {
  (void)in_sizes; (void)n_in; (void)out_size; (void)ws_size;
  const float* u  = (const float*)d_in[0];
  const float* x  = (const float*)d_in[1];
  const float* W1 = (const float*)d_in[2];
  const float* b1 = (const float*)d_in[3];
  const float* W2 = (const float*)d_in[4];
  const float* b2 = (const float*)d_in[5];
  const float* W3 = (const float*)d_in[6];
  const float* b3 = (const float*)d_in[7];
  float* out = (float*)d_out;
  char*  ws  = (char*)d_ws;

  float* bands = (float*)(ws + OFF_BANDS);
  u16*   abf   = (u16*)(ws + OFF_ABF);
  u16*   bfr   = (u16*)(ws + OFF_BFRAG);
  u16*   urev  = (u16*)(ws + OFF_UREV);

  k_bands<<<dim3(9, 3), 256, 0, stream>>>(x, W1, b1, W2, b2, W3, b3, bands);
  k_interp<<<1, 1024, 0, stream>>>(bands, abf);
  k_urev<<<dim3(5, 1024), 256, 0, stream>>>(u, urev);
  k_bfrag<<<258, 256, 0, stream>>>(abf, bfr);
  k_lastcol<<<1024, 256, 0, stream>>>(urev, abf, out);
  k_gemm<<<512, 256, 0, stream>>>(urev, bfr, out);
}